// Round 6
// baseline (218.285 us; speedup 1.0000x reference)
//
#include <hip/hip_runtime.h>
#include <hip/hip_bf16.h>
#include <stdint.h>

typedef __bf16 bf16;
typedef __bf16 bf16x8 __attribute__((ext_vector_type(8)));
typedef __bf16 bf16x4v __attribute__((ext_vector_type(4)));
typedef float  f32x4  __attribute__((ext_vector_type(4)));
typedef float  f32x16 __attribute__((ext_vector_type(16)));
typedef unsigned int u32x4 __attribute__((ext_vector_type(4)));

#define NB    8
#define SEQ   2048
#define EMB   512
#define NHEAD 8
#define HD    64

static __device__ __forceinline__ f32x4 mfma16(bf16x8 a, bf16x8 b, f32x4 c) {
    return __builtin_amdgcn_mfma_f32_16x16x32_bf16(a, b, c, 0, 0, 0);
}
static __device__ __forceinline__ f32x16 mfma32(bf16x8 a, bf16x8 b, f32x16 c) {
    return __builtin_amdgcn_mfma_f32_32x32x16_bf16(a, b, c, 0, 0, 0);
}
static __device__ __forceinline__ float ex2(float x) {
    float r; asm("v_exp_f32 %0, %1" : "=v"(r) : "v"(x)); return r;
}
static __device__ __forceinline__ unsigned pkbf(float lo, float hi) {
    unsigned d; asm("v_cvt_pk_bf16_f32 %0, %1, %2" : "=v"(d) : "v"(lo), "v"(hi)); return d;
}
static __device__ __forceinline__ float max3(float a, float b, float c) {
    return fmaxf(fmaxf(a, b), c);   // fuses to v_max3_f32
}
static __device__ __forceinline__ void gload_lds16(const void* g, void* l) {
    __builtin_amdgcn_global_load_lds(
        (const __attribute__((address_space(1))) unsigned int*)g,
        (__attribute__((address_space(3))) unsigned int*)l, 16, 0, 0);
}
#define PRIO1 __builtin_amdgcn_s_setprio(1)
#define PRIO0 __builtin_amdgcn_s_setprio(0)

// ---------------------------------------------------------------------------
// Weights: fp32 [k][n] -> bf16 transposed [n][k], 4 matrices
// ---------------------------------------------------------------------------
__global__ __launch_bounds__(256) void prep_weights(
    const float* __restrict__ Wv, const float* __restrict__ Wk,
    const float* __restrict__ Wq, const float* __restrict__ Wo,
    bf16* __restrict__ wt)
{
    int idx = blockIdx.x * 256 + threadIdx.x;
    int w   = idx >> 18;
    int rem = idx & 262143;
    int k   = rem >> 9;
    int n   = rem & 511;
    const float* src = (w == 0) ? Wv : (w == 1) ? Wk : (w == 2) ? Wq : Wo;
    wt[(size_t)w * 262144 + (size_t)n * 512 + k] = (bf16)src[k * 512 + n];
}

// ---------------------------------------------------------------------------
// GEMM: C[16384][512] = A[16384][512] * W, B given transposed bf16 (unchanged)
// ---------------------------------------------------------------------------
template <bool A_F32, bool FINAL>
__global__ __launch_bounds__(256) void gemm_kernel(
    const void* __restrict__ Ap, const bf16* __restrict__ Bt,
    void* __restrict__ Cp, const float* __restrict__ bias)
{
    __shared__ __align__(16) bf16 As[128][72];
    __shared__ __align__(16) bf16 Bs[128][72];

    const int t    = threadIdx.x;
    const int lane = t & 63;
    const int wave = t >> 6;
    const int wr   = wave >> 1, wc = wave & 1;
    const int l15  = lane & 15, lg = lane >> 4;
    const long row0 = (long)blockIdx.x * 128;
    const int  col0 = blockIdx.y * 128;

    f32x4 acc[4][4];
#pragma unroll
    for (int i = 0; i < 4; i++)
#pragma unroll
        for (int j = 0; j < 4; j++) acc[i][j] = (f32x4){0.f, 0.f, 0.f, 0.f};

    for (int k0 = 0; k0 < 512; k0 += 64) {
        __syncthreads();
        if (A_F32) {
            const float* A = (const float*)Ap;
#pragma unroll
            for (int i = 0; i < 8; i++) {
                int c  = t + 256 * i;
                int r  = c >> 4;
                int cc = (c & 15) * 4;
                f32x4 v = *(const f32x4*)(A + (row0 + r) * 512 + k0 + cc);
                bf16x4v pk = { (bf16)v[0], (bf16)v[1], (bf16)v[2], (bf16)v[3] };
                *(bf16x4v*)&As[r][cc] = pk;
            }
        } else {
            const bf16* A = (const bf16*)Ap;
#pragma unroll
            for (int i = 0; i < 4; i++) {
                int c  = t + 256 * i;
                int r  = c >> 3;
                int cc = (c & 7) * 8;
                *(bf16x8*)&As[r][cc] = *(const bf16x8*)(A + (row0 + r) * 512 + k0 + cc);
            }
        }
#pragma unroll
        for (int i = 0; i < 4; i++) {
            int c  = t + 256 * i;
            int r  = c >> 3;
            int cc = (c & 7) * 8;
            *(bf16x8*)&Bs[r][cc] = *(const bf16x8*)(Bt + (size_t)(col0 + r) * 512 + k0 + cc);
        }
        __syncthreads();
#pragma unroll
        for (int kc = 0; kc < 64; kc += 32) {
            bf16x8 af[4], bfv[4];
#pragma unroll
            for (int mb = 0; mb < 4; mb++)
                af[mb] = *(bf16x8*)&As[wr * 64 + mb * 16 + l15][kc + lg * 8];
#pragma unroll
            for (int nb = 0; nb < 4; nb++)
                bfv[nb] = *(bf16x8*)&Bs[wc * 64 + nb * 16 + l15][kc + lg * 8];
#pragma unroll
            for (int mb = 0; mb < 4; mb++)
#pragma unroll
                for (int nb = 0; nb < 4; nb++)
                    acc[mb][nb] = mfma16(af[mb], bfv[nb], acc[mb][nb]);
        }
    }

#pragma unroll
    for (int mb = 0; mb < 4; mb++)
#pragma unroll
        for (int nb = 0; nb < 4; nb++)
#pragma unroll
            for (int r = 0; r < 4; r++) {
                long grow = row0 + wr * 64 + mb * 16 + lg * 4 + r;
                int  gcol = col0 + wc * 64 + nb * 16 + l15;
                float v = acc[mb][nb][r];
                if (FINAL) {
                    ((float*)Cp)[grow * 512 + gcol] = v + bias[gcol];
                } else {
                    ((bf16*)Cp)[grow * 512 + gcol] = (bf16)v;
                }
            }
}

// ---------------------------------------------------------------------------
// Flash attention, swapped-QK^T 32x32x16.
// R6: 1024 thr = 16 waves x 32 q (4 waves/SIMD, 2x latency hiding vs R5),
// SAME per-CU staging/FETCH (one block/CU, grid 4x8x8). 2-tile epochs.
// Staging roles: wave w stages slot (w&7) of tile (w>>3).
// Epilogue Ob aliases over K/V LDS after final barrier. ~120 VGPR.
// ---------------------------------------------------------------------------
__global__ __launch_bounds__(1024, 4) void attn_kernel(
    const bf16* __restrict__ Qg, const bf16* __restrict__ Kg,
    const bf16* __restrict__ Vg, const int* __restrict__ mask,
    bf16* __restrict__ ctx)
{
    // LDS: [0,32768) K bufs 4x8192B; [32768,65536) V bufs 4x8192B;
    // [0,73728) Ob (aliased, after final barrier); [73728,73792) mask flags
    __shared__ __align__(16) char smem[73792];
    int* mflags = (int*)(smem + 73728);

    const int t    = threadIdx.x;
    const int lane = t & 63;
    const int w    = t >> 6;          // 0..15
    const int wA   = w & 7;           // staging slot
    const int wT   = w >> 3;          // staging tile (0=A,1=B)
    const int l31  = lane & 31;
    const int hi   = lane >> 5;
    const int qt = blockIdx.x, h = blockIdx.y, n = blockIdx.z;

    const size_t nbase   = (size_t)n * SEQ;
    const size_t headoff = (size_t)h * 64;
    const int q0 = qt * 512 + w * 32;

    // block-wide "mask all ones" flag (1024 thr x 2 = 2048 entries)
    {
        const int* mp0 = mask + n * SEQ + t * 2;
        int mok = (mp0[0] != 0) & (mp0[1] != 0);
        unsigned long long b = __ballot(mok);
        if (lane == 0) mflags[w] = (b == ~0ULL) ? 1 : 0;
    }

    // Q fragments: B-operand, col=q=l31, k-dim d = ds*16 + hi*8 + j
    bf16x8 qf[4];
#pragma unroll
    for (int ds = 0; ds < 4; ++ds)
        qf[ds] = *(const bf16x8*)(Qg + (nbase + q0 + l31) * 512 + headoff + ds * 16 + hi * 8);

    f32x16 o[2] = {};             // [db], O^T: row=d-local, col=q
    float m_run = -1e30f;
    float l_run = 0.f;

    // staging source pointers (per-wave role: slot wA, tiles wT, wT+2, ...)
    const bf16* kg = Kg + (nbase + wA * 8 + (lane >> 3)) * 512 + headoff + (((lane & 7) ^ (lane >> 3)) << 3);
    const bf16* vg = Vg + (nbase + lane) * 512 + headoff + wA * 8;
    const int*  mp = mask + n * SEQ;

#define VSCAT(VR, BUF) do {                                                   \
        char* vbp = smem + 32768 + (BUF) * 8192;                              \
        _Pragma("unroll") for (int j = 0; j < 8; ++j)                         \
            *(bf16*)(vbp + (8 * wA + j) * 128 + ((2 * lane) ^ (j << 4))) = (VR)[j]; \
    } while (0)

    // prologue: stage tiles 0,1 (wave role: tile wT into buf wT)
    bf16x8 vr;
    gload_lds16(kg + (size_t)wT * 64 * 512, smem + wT * 8192 + wA * 1024);
    vr = *(const bf16x8*)(vg + (size_t)wT * 64 * 512);
    VSCAT(vr, wT);
    __syncthreads();
    int maskall = 1;
#pragma unroll
    for (int i = 0; i < 16; ++i) maskall &= mflags[i];

    const float SC = 0.18033688011f;   // 0.125 * log2(e)

    f32x16 p[2];
    u32x4  bq[4];

#define QK_TILE(BUF) do {                                                     \
        const char* kbb = smem + (BUF) * 8192;                                \
        f32x16 zz = {};                                                       \
        p[0] = zz; p[1] = zz;                                                 \
        PRIO1;                                                                \
        _Pragma("unroll")                                                     \
        for (int ds = 0; ds < 4; ++ds) {                                      \
            int sw = (ds * 32 + hi * 16) ^ ((l31 & 7) << 4);                  \
            bf16x8 kf0 = *(const bf16x8*)(kbb + l31 * 128 + sw);              \
            bf16x8 kf1 = *(const bf16x8*)(kbb + (32 + l31) * 128 + sw);       \
            p[0] = mfma32(kf0, qf[ds], p[0]);                                 \
            p[1] = mfma32(kf1, qf[ds], p[1]);                                 \
        }                                                                     \
        PRIO0;                                                                \
    } while (0)

#define MASK_TILE(T) do {                                                     \
        if (!maskall) {                                                       \
            int mv = mp[(T) * 64 + lane];                                     \
            unsigned long long mb = __ballot(mv != 0);                        \
            if (mb != ~0ULL) {                                                \
                _Pragma("unroll") for (int kb = 0; kb < 2; ++kb) {            \
                    float* pp = (float*)&p[kb];                               \
                    _Pragma("unroll") for (int r = 0; r < 16; ++r) {          \
                        int kk = kb * 32 + (r & 3) + 8 * (r >> 2) + 4 * hi;   \
                        if (!((mb >> kk) & 1)) pp[r] = -1e30f;                \
                    }                                                         \
                }                                                             \
            }                                                                 \
        }                                                                     \
    } while (0)

#define SM_PACK do {                                                          \
        float* p0 = (float*)&p[0];                                            \
        float* p1 = (float*)&p[1];                                            \
        float g0 = max3(p0[0], p0[1], p0[2]);                                 \
        float g1 = max3(p0[3], p0[4], p0[5]);                                 \
        float g2 = max3(p0[6], p0[7], p0[8]);                                 \
        float g3 = max3(p0[9], p0[10], p0[11]);                               \
        float g4 = max3(p0[12], p0[13], p0[14]);                              \
        float g5 = max3(p0[15], p1[0], p1[1]);                                \
        float g6 = max3(p1[2], p1[3], p1[4]);                                 \
        float g7 = max3(p1[5], p1[6], p1[7]);                                 \
        float g8 = max3(p1[8], p1[9], p1[10]);                                \
        float g9 = max3(p1[11], p1[12], p1[13]);                              \
        float g10 = fmaxf(p1[14], p1[15]);                                    \
        float t0 = max3(g0, g1, g2), t1 = max3(g3, g4, g5);                   \
        float t2 = max3(g6, g7, g8), t3 = max3(g9, g10, t0);                  \
        float tm = max3(t1, t2, t3);                                          \
        float tms = tm * SC;                                                  \
        float rmax = fmaxf(tms, __shfl_xor(tms, 32));                         \
        if (!__all(rmax <= m_run + 8.0f)) {                                   \
            float mn  = fmaxf(m_run, rmax);                                   \
            float fac = ex2(m_run - mn);                                      \
            _Pragma("unroll") for (int db = 0; db < 2; ++db) {                \
                float* oo = (float*)&o[db];                                   \
                _Pragma("unroll") for (int r = 0; r < 16; ++r) oo[r] *= fac;  \
            }                                                                 \
            l_run *= fac; m_run = mn;                                         \
        }                                                                     \
        float negm = -m_run;                                                  \
        float sa0 = 0.f, sa1 = 0.f, sa2 = 0.f, sa3 = 0.f;                     \
        _Pragma("unroll") for (int r = 0; r < 16; r += 4) {                   \
            float e0 = ex2(fmaf(p0[r],   SC, negm)); p0[r]   = e0; sa0 += e0; \
            float e1 = ex2(fmaf(p0[r+1], SC, negm)); p0[r+1] = e1; sa1 += e1; \
            float e2 = ex2(fmaf(p0[r+2], SC, negm)); p0[r+2] = e2; sa2 += e2; \
            float e3 = ex2(fmaf(p0[r+3], SC, negm)); p0[r+3] = e3; sa3 += e3; \
        }                                                                     \
        _Pragma("unroll") for (int r = 0; r < 16; r += 4) {                   \
            float e0 = ex2(fmaf(p1[r],   SC, negm)); p1[r]   = e0; sa0 += e0; \
            float e1 = ex2(fmaf(p1[r+1], SC, negm)); p1[r+1] = e1; sa1 += e1; \
            float e2 = ex2(fmaf(p1[r+2], SC, negm)); p1[r+2] = e2; sa2 += e2; \
            float e3 = ex2(fmaf(p1[r+3], SC, negm)); p1[r+3] = e3; sa3 += e3; \
        }                                                                     \
        float sl = (sa0 + sa1) + (sa2 + sa3);                                 \
        l_run += sl + __shfl_xor(sl, 32);                                     \
        _Pragma("unroll")                                                     \
        for (int ks = 0; ks < 4; ++ks) {                                      \
            float* ps = (ks >> 1) ? p1 : p0;                                  \
            int bo = (ks & 1) * 8;                                            \
            unsigned A  = pkbf(ps[bo + 0], ps[bo + 1]);                       \
            unsigned B  = pkbf(ps[bo + 2], ps[bo + 3]);                       \
            unsigned C  = pkbf(ps[bo + 4], ps[bo + 5]);                       \
            unsigned Dw = pkbf(ps[bo + 6], ps[bo + 7]);                       \
            unsigned xA = __shfl_xor(A, 32), xB = __shfl_xor(B, 32);          \
            unsigned xC = __shfl_xor(C, 32), xD = __shfl_xor(Dw, 32);         \
            unsigned w0 = hi ? xC : A, w1 = hi ? xD : B;                      \
            unsigned w2 = hi ? C : xA, w3 = hi ? Dw : xB;                     \
            bq[ks] = (u32x4){w0, w1, w2, w3};                                 \
        }                                                                     \
    } while (0)

#define PV_TILE(BUF) do {                                                     \
        const char* vbb = smem + 32768 + (BUF) * 8192;                        \
        PRIO1;                                                                \
        _Pragma("unroll")                                                     \
        for (int ks = 0; ks < 4; ++ks) {                                      \
            int sw = (ks * 32 + hi * 16) ^ ((l31 & 7) << 4);                  \
            bf16x8 vf0 = *(const bf16x8*)(vbb + l31 * 128 + sw);              \
            bf16x8 vf1 = *(const bf16x8*)(vbb + (32 + l31) * 128 + sw);       \
            union { u32x4 u; bf16x8 v; } c0;                                  \
            c0.u = bq[ks];                                                    \
            o[0] = mfma32(vf0, c0.v, o[0]);                                   \
            o[1] = mfma32(vf1, c0.v, o[1]);                                   \
        }                                                                     \
        PRIO0;                                                                \
    } while (0)

    for (int e = 0; e < 16; ++e) {
        const int bA = (e & 1) * 2, bB = bA + 1;
        // T14: issue next-epoch staging early (wave role: tile 2e+2+wT)
        if (e < 15) {
            gload_lds16(kg + (size_t)(2 * e + 2 + wT) * 64 * 512,
                        smem + ((bA ^ 2) + wT) * 8192 + wA * 1024);
            vr = *(const bf16x8*)(vg + (size_t)(2 * e + 2 + wT) * 64 * 512);
        }
        // tile A = 2e
        QK_TILE(bA);
        MASK_TILE(2 * e);
        SM_PACK;
        PV_TILE(bA);
        // tile B = 2e+1
        QK_TILE(bB);
        MASK_TILE(2 * e + 1);
        SM_PACK;
        PV_TILE(bB);
        // late scatter for next epoch
        if (e < 15) VSCAT(vr, (bA ^ 2) + wT);
        __syncthreads();
    }

    // ---- epilogue: O^T -> LDS transpose -> coalesced bf16 store ----
    // Ob aliases over K/V buffers (safe after the final barrier).
    {
        float inv = 1.f / l_run;
        bf16* ob = (bf16*)(smem + w * 4608);   // 32 rows x 72 cols
#pragma unroll
        for (int db = 0; db < 2; ++db) {
            float* oo = (float*)&o[db];
#pragma unroll
            for (int r = 0; r < 16; ++r) {
                int d = db * 32 + (r & 3) + 8 * (r >> 2) + 4 * hi;
                ob[l31 * 72 + d] = (bf16)(oo[r] * inv);
            }
        }
#pragma unroll
        for (int i = 0; i < 2; ++i)
#pragma unroll
            for (int half = 0; half < 2; ++half) {
                int ql = i * 16 + (lane >> 2);
                int d8 = (lane & 3) * 8 + half * 32;
                bf16x8 vv = *(const bf16x8*)(ob + ql * 72 + d8);
                *(bf16x8*)(ctx + (nbase + q0 + ql) * 512 + headoff + d8) = vv;
            }
    }
#undef VSCAT
#undef QK_TILE
#undef MASK_TILE
#undef SM_PACK
#undef PV_TILE
}

// ---------------------------------------------------------------------------
extern "C" void kernel_launch(void* const* d_in, const int* in_sizes, int n_in,
                              void* d_out, int out_size, void* d_ws, size_t ws_size,
                              hipStream_t stream) {
    (void)in_sizes; (void)n_in; (void)out_size; (void)ws_size;
    const float* values = (const float*)d_in[0];
    const float* keys   = (const float*)d_in[1];
    const float* query  = (const float*)d_in[2];
    const int*   mask   = (const int*)d_in[3];
    const float* Wv = (const float*)d_in[4];
    const float* Wk = (const float*)d_in[5];
    const float* Wq = (const float*)d_in[6];
    const float* Wo = (const float*)d_in[7];
    const float* bo = (const float*)d_in[8];
    float* out = (float*)d_out;

    char* ws = (char*)d_ws;
    bf16* wt = (bf16*)(ws);                       //  2 MB: 4 x [512][512]
    bf16* Qb = (bf16*)(ws + ((size_t)2  << 20));  // 16 MB
    bf16* Kb = (bf16*)(ws + ((size_t)18 << 20));  // 16 MB
    bf16* Vb = (bf16*)(ws + ((size_t)34 << 20));  // 16 MB
    bf16* Cb = (bf16*)(ws + ((size_t)50 << 20));  // 16 MB

    prep_weights<<<4096, 256, 0, stream>>>(Wv, Wk, Wq, Wo, wt);
    gemm_kernel<true, false><<<dim3(128, 4), 256, 0, stream>>>(values, wt,              Vb, nullptr);
    gemm_kernel<true, false><<<dim3(128, 4), 256, 0, stream>>>(keys,   wt + 262144,     Kb, nullptr);
    gemm_kernel<true, false><<<dim3(128, 4), 256, 0, stream>>>(query,  wt + 2 * 262144, Qb, nullptr);
    attn_kernel<<<dim3(4, 8, 8), 1024, 0, stream>>>(Qb, Kb, Vb, mask, Cb);
    gemm_kernel<false, true><<<dim3(128, 4), 256, 0, stream>>>(Cb, wt + 3 * 262144, out, bo);
}

// Round 7
// 212.399 us; speedup vs baseline: 1.0277x; 1.0277x over previous
//
#include <hip/hip_runtime.h>
#include <hip/hip_bf16.h>
#include <stdint.h>

typedef __bf16 bf16;
typedef __bf16 bf16x8 __attribute__((ext_vector_type(8)));
typedef __bf16 bf16x4v __attribute__((ext_vector_type(4)));
typedef float  f32x4  __attribute__((ext_vector_type(4)));
typedef float  f32x16 __attribute__((ext_vector_type(16)));
typedef unsigned int u32x4 __attribute__((ext_vector_type(4)));

#define NB    8
#define SEQ   2048
#define EMB   512
#define NHEAD 8
#define HD    64

static __device__ __forceinline__ f32x4 mfma16(bf16x8 a, bf16x8 b, f32x4 c) {
    return __builtin_amdgcn_mfma_f32_16x16x32_bf16(a, b, c, 0, 0, 0);
}
static __device__ __forceinline__ f32x16 mfma32(bf16x8 a, bf16x8 b, f32x16 c) {
    return __builtin_amdgcn_mfma_f32_32x32x16_bf16(a, b, c, 0, 0, 0);
}
static __device__ __forceinline__ float ex2(float x) {
    float r; asm("v_exp_f32 %0, %1" : "=v"(r) : "v"(x)); return r;
}
static __device__ __forceinline__ unsigned pkbf(float lo, float hi) {
    unsigned d; asm("v_cvt_pk_bf16_f32 %0, %1, %2" : "=v"(d) : "v"(lo), "v"(hi)); return d;
}
static __device__ __forceinline__ float max3(float a, float b, float c) {
    return fmaxf(fmaxf(a, b), c);   // fuses to v_max3_f32
}
#define PRIO1 __builtin_amdgcn_s_setprio(1)
#define PRIO0 __builtin_amdgcn_s_setprio(0)

// ---------------------------------------------------------------------------
// Weights: fp32 [k][n] -> bf16 transposed [n][k], 4 matrices
// ---------------------------------------------------------------------------
__global__ __launch_bounds__(256) void prep_weights(
    const float* __restrict__ Wv, const float* __restrict__ Wk,
    const float* __restrict__ Wq, const float* __restrict__ Wo,
    bf16* __restrict__ wt)
{
    int idx = blockIdx.x * 256 + threadIdx.x;
    int w   = idx >> 18;
    int rem = idx & 262143;
    int k   = rem >> 9;
    int n   = rem & 511;
    const float* src = (w == 0) ? Wv : (w == 1) ? Wk : (w == 2) ? Wq : Wo;
    wt[(size_t)w * 262144 + (size_t)n * 512 + k] = (bf16)src[k * 512 + n];
}

// ---------------------------------------------------------------------------
// GEMM: C[16384][512] = A[16384][512] * W, B given transposed bf16.
// VT: write output TRANSPOSED per batch: VbT[n][d][key] (for attention PV).
// ---------------------------------------------------------------------------
template <bool A_F32, bool FINAL, bool VT>
__global__ __launch_bounds__(256) void gemm_kernel(
    const void* __restrict__ Ap, const bf16* __restrict__ Bt,
    void* __restrict__ Cp, const float* __restrict__ bias)
{
    __shared__ __align__(16) bf16 As[128][72];
    __shared__ __align__(16) bf16 Bs[128][72];

    const int t    = threadIdx.x;
    const int lane = t & 63;
    const int wave = t >> 6;
    const int wr   = wave >> 1, wc = wave & 1;
    const int l15  = lane & 15, lg = lane >> 4;
    const long row0 = (long)blockIdx.x * 128;
    const int  col0 = blockIdx.y * 128;

    f32x4 acc[4][4];
#pragma unroll
    for (int i = 0; i < 4; i++)
#pragma unroll
        for (int j = 0; j < 4; j++) acc[i][j] = (f32x4){0.f, 0.f, 0.f, 0.f};

    for (int k0 = 0; k0 < 512; k0 += 64) {
        __syncthreads();
        if (A_F32) {
            const float* A = (const float*)Ap;
#pragma unroll
            for (int i = 0; i < 8; i++) {
                int c  = t + 256 * i;
                int r  = c >> 4;
                int cc = (c & 15) * 4;
                f32x4 v = *(const f32x4*)(A + (row0 + r) * 512 + k0 + cc);
                bf16x4v pk = { (bf16)v[0], (bf16)v[1], (bf16)v[2], (bf16)v[3] };
                *(bf16x4v*)&As[r][cc] = pk;
            }
        } else {
            const bf16* A = (const bf16*)Ap;
#pragma unroll
            for (int i = 0; i < 4; i++) {
                int c  = t + 256 * i;
                int r  = c >> 3;
                int cc = (c & 7) * 8;
                *(bf16x8*)&As[r][cc] = *(const bf16x8*)(A + (row0 + r) * 512 + k0 + cc);
            }
        }
#pragma unroll
        for (int i = 0; i < 4; i++) {
            int c  = t + 256 * i;
            int r  = c >> 3;
            int cc = (c & 7) * 8;
            *(bf16x8*)&Bs[r][cc] = *(const bf16x8*)(Bt + (size_t)(col0 + r) * 512 + k0 + cc);
        }
        __syncthreads();
#pragma unroll
        for (int kc = 0; kc < 64; kc += 32) {
            bf16x8 af[4], bfv[4];
#pragma unroll
            for (int mb = 0; mb < 4; mb++)
                af[mb] = *(bf16x8*)&As[wr * 64 + mb * 16 + l15][kc + lg * 8];
#pragma unroll
            for (int nb = 0; nb < 4; nb++)
                bfv[nb] = *(bf16x8*)&Bs[wc * 64 + nb * 16 + l15][kc + lg * 8];
#pragma unroll
            for (int mb = 0; mb < 4; mb++)
#pragma unroll
                for (int nb = 0; nb < 4; nb++)
                    acc[mb][nb] = mfma16(af[mb], bfv[nb], acc[mb][nb]);
        }
    }

    if constexpr (VT) {
        // transpose epilogue: acc -> LDS [d][key] -> coalesced-per-row store
        __shared__ __align__(16) bf16 Cs[128][138];   // stride 138 el: conflict-free
#pragma unroll
        for (int mb = 0; mb < 4; mb++)
#pragma unroll
            for (int nb = 0; nb < 4; nb++)
#pragma unroll
                for (int r = 0; r < 4; r++) {
                    int keyl = wr * 64 + mb * 16 + lg * 4 + r;
                    int dl   = wc * 64 + nb * 16 + l15;
                    Cs[dl][keyl] = (bf16)acc[mb][nb][r];
                }
        __syncthreads();
        const int n_idx = (int)(row0 >> 11);
        const int key0  = (int)(row0 & 2047);
        const int dl    = t >> 1;
        const int half  = t & 1;
        bf16* dst = (bf16*)Cp + ((size_t)n_idx * 512 + col0 + dl) * 2048 + key0 + half * 64;
#pragma unroll
        for (int c = 0; c < 8; ++c)
            *(bf16x8*)(dst + c * 8) = *(const bf16x8*)&Cs[dl][half * 64 + c * 8];
    } else {
#pragma unroll
        for (int mb = 0; mb < 4; mb++)
#pragma unroll
            for (int nb = 0; nb < 4; nb++)
#pragma unroll
                for (int r = 0; r < 4; r++) {
                    long grow = row0 + wr * 64 + mb * 16 + lg * 4 + r;
                    int  gcol = col0 + wc * 64 + nb * 16 + l15;
                    float v = acc[mb][nb][r];
                    if (FINAL) {
                        ((float*)Cp)[grow * 512 + gcol] = v + bias[gcol];
                    } else {
                        ((bf16*)Cp)[grow * 512 + gcol] = (bf16)v;
                    }
                }
    }
}

// ---------------------------------------------------------------------------
// Flash attention, swapped-QK^T 32x32x16, R7: NO K/V LDS staging, NO main-loop
// barriers. K frags direct from global (row-major Kb, L1/L2-resident);
// V frags direct from pre-transposed VbT[n][d][key]. Waves fully independent.
// Grid (h, n, qt) so qt-blocks sharing K/V land on one XCD.
// 512 thr = 8 waves x 64 q.
// ---------------------------------------------------------------------------
__global__ __launch_bounds__(512, 2) void attn_kernel(
    const bf16* __restrict__ Qg, const bf16* __restrict__ Kg,
    const bf16* __restrict__ Vtg, const int* __restrict__ maskp,
    bf16* __restrict__ ctx)
{
    __shared__ __align__(16) bf16 Ob[8][32 * 72];
    __shared__ int mflags[8];

    const int t    = threadIdx.x;
    const int lane = t & 63;
    const int w    = t >> 6;
    const int l31  = lane & 31;
    const int hi   = lane >> 5;
    const int h = blockIdx.x, n = blockIdx.y, qt = blockIdx.z;

    const size_t nbase   = (size_t)n * SEQ;
    const size_t headoff = (size_t)h * 64;
    const int q0 = qt * 512 + w * 64;

    // block-wide "mask all ones" flag
    {
        const int* mp0 = maskp + n * SEQ + t * 4;
        int mok = (mp0[0] != 0) & (mp0[1] != 0) & (mp0[2] != 0) & (mp0[3] != 0);
        unsigned long long b = __ballot(mok);
        if (lane == 0) mflags[w] = (b == ~0ULL) ? 1 : 0;
    }
    __syncthreads();
    int maskall = 1;
#pragma unroll
    for (int i = 0; i < 8; ++i) maskall &= mflags[i];

    // Q fragments: B-operand, col=q=l31, k-dim d = ds*16 + hi*8 + j
    bf16x8 qf[2][4];
#pragma unroll
    for (int qb = 0; qb < 2; ++qb)
#pragma unroll
        for (int ds = 0; ds < 4; ++ds)
            qf[qb][ds] = *(const bf16x8*)(Qg + (nbase + q0 + qb * 32 + l31) * 512 + headoff + ds * 16 + hi * 8);

    f32x16 o[2][2] = {};          // [db][qb], O^T: row=d-local, col=q
    float m_run[2] = {-1e30f, -1e30f};
    float l_run[2] = {0.f, 0.f};

    const bf16* kb = Kg + nbase * 512 + headoff;                  // +(kt*64+key)*512 + d
    const bf16* vb = Vtg + ((size_t)n * 512 + h * 64) * 2048;     // + d*2048 + key
    const int*  mp = maskp + n * SEQ;

    const float SC = 0.18033688011f;   // 0.125 * log2(e)

    f32x16 p[2][2];
    u32x4  bq[2][4];
    bf16x8 kf[2][4];
    bf16x8 vf[2][4];

#define KLOAD(KT) do {                                                        \
        _Pragma("unroll") for (int kk = 0; kk < 2; ++kk)                      \
        _Pragma("unroll") for (int ds = 0; ds < 4; ++ds)                      \
            kf[kk][ds] = *(const bf16x8*)(kb + (size_t)((KT) * 64 + kk * 32 + l31) * 512 + ds * 16 + hi * 8); \
    } while (0)

#define VLOAD(KT) do {                                                        \
        _Pragma("unroll") for (int dh = 0; dh < 2; ++dh)                      \
        _Pragma("unroll") for (int ks = 0; ks < 4; ++ks)                      \
            vf[dh][ks] = *(const bf16x8*)(vb + (size_t)(dh * 32 + l31) * 2048 + (KT) * 64 + ks * 16 + hi * 8); \
    } while (0)

#define QK_TILE do {                                                          \
        f32x16 zz = {};                                                       \
        p[0][0] = zz; p[0][1] = zz; p[1][0] = zz; p[1][1] = zz;               \
        PRIO1;                                                                \
        _Pragma("unroll")                                                     \
        for (int ds = 0; ds < 4; ++ds) {                                      \
            p[0][0] = mfma32(kf[0][ds], qf[0][ds], p[0][0]);                  \
            p[1][0] = mfma32(kf[0][ds], qf[1][ds], p[1][0]);                  \
            p[0][1] = mfma32(kf[1][ds], qf[0][ds], p[0][1]);                  \
            p[1][1] = mfma32(kf[1][ds], qf[1][ds], p[1][1]);                  \
        }                                                                     \
        PRIO0;                                                                \
    } while (0)

#define MASK_TILE(T) do {                                                     \
        if (!maskall) {                                                       \
            int mv = mp[(T) * 64 + lane];                                     \
            unsigned long long mb = __ballot(mv != 0);                        \
            if (mb != ~0ULL) {                                                \
                _Pragma("unroll") for (int qb = 0; qb < 2; ++qb)              \
                _Pragma("unroll") for (int kk = 0; kk < 2; ++kk) {            \
                    float* pp = (float*)&p[qb][kk];                           \
                    _Pragma("unroll") for (int r = 0; r < 16; ++r) {          \
                        int kkk = kk * 32 + (r & 3) + 8 * (r >> 2) + 4 * hi;  \
                        if (!((mb >> kkk) & 1)) pp[r] = -1e30f;               \
                    }                                                         \
                }                                                             \
            }                                                                 \
        }                                                                     \
    } while (0)

#define SM_PACK do {                                                          \
        _Pragma("unroll")                                                     \
        for (int qb = 0; qb < 2; ++qb) {                                      \
            float* p0 = (float*)&p[qb][0];                                    \
            float* p1 = (float*)&p[qb][1];                                    \
            float g0 = max3(p0[0], p0[1], p0[2]);                             \
            float g1 = max3(p0[3], p0[4], p0[5]);                             \
            float g2 = max3(p0[6], p0[7], p0[8]);                             \
            float g3 = max3(p0[9], p0[10], p0[11]);                           \
            float g4 = max3(p0[12], p0[13], p0[14]);                          \
            float g5 = max3(p0[15], p1[0], p1[1]);                            \
            float g6 = max3(p1[2], p1[3], p1[4]);                             \
            float g7 = max3(p1[5], p1[6], p1[7]);                             \
            float g8 = max3(p1[8], p1[9], p1[10]);                            \
            float g9 = max3(p1[11], p1[12], p1[13]);                          \
            float g10 = fmaxf(p1[14], p1[15]);                                \
            float t0 = max3(g0, g1, g2), t1 = max3(g3, g4, g5);               \
            float t2 = max3(g6, g7, g8), t3 = max3(g9, g10, t0);              \
            float tm = max3(t1, t2, t3);                                      \
            float tms = tm * SC;                                              \
            float rmax = fmaxf(tms, __shfl_xor(tms, 32));                     \
            if (!__all(rmax <= m_run[qb] + 8.0f)) {                           \
                float mn  = fmaxf(m_run[qb], rmax);                           \
                float fac = ex2(m_run[qb] - mn);                              \
                _Pragma("unroll") for (int db = 0; db < 2; ++db) {            \
                    float* oo = (float*)&o[db][qb];                           \
                    _Pragma("unroll") for (int r = 0; r < 16; ++r) oo[r] *= fac; \
                }                                                             \
                l_run[qb] *= fac; m_run[qb] = mn;                             \
            }                                                                 \
            float negm = -m_run[qb];                                          \
            float sa0 = 0.f, sa1 = 0.f, sa2 = 0.f, sa3 = 0.f;                 \
            _Pragma("unroll") for (int r = 0; r < 16; r += 4) {               \
                float e0 = ex2(fmaf(p0[r],   SC, negm)); p0[r]   = e0; sa0 += e0; \
                float e1 = ex2(fmaf(p0[r+1], SC, negm)); p0[r+1] = e1; sa1 += e1; \
                float e2 = ex2(fmaf(p0[r+2], SC, negm)); p0[r+2] = e2; sa2 += e2; \
                float e3 = ex2(fmaf(p0[r+3], SC, negm)); p0[r+3] = e3; sa3 += e3; \
            }                                                                 \
            _Pragma("unroll") for (int r = 0; r < 16; r += 4) {               \
                float e0 = ex2(fmaf(p1[r],   SC, negm)); p1[r]   = e0; sa0 += e0; \
                float e1 = ex2(fmaf(p1[r+1], SC, negm)); p1[r+1] = e1; sa1 += e1; \
                float e2 = ex2(fmaf(p1[r+2], SC, negm)); p1[r+2] = e2; sa2 += e2; \
                float e3 = ex2(fmaf(p1[r+3], SC, negm)); p1[r+3] = e3; sa3 += e3; \
            }                                                                 \
            float sl = (sa0 + sa1) + (sa2 + sa3);                             \
            l_run[qb] += sl + __shfl_xor(sl, 32);                             \
            _Pragma("unroll")                                                 \
            for (int ks = 0; ks < 4; ++ks) {                                  \
                float* ps = (ks >> 1) ? p1 : p0;                              \
                int bo = (ks & 1) * 8;                                        \
                unsigned A  = pkbf(ps[bo + 0], ps[bo + 1]);                   \
                unsigned B  = pkbf(ps[bo + 2], ps[bo + 3]);                   \
                unsigned C  = pkbf(ps[bo + 4], ps[bo + 5]);                   \
                unsigned Dw = pkbf(ps[bo + 6], ps[bo + 7]);                   \
                unsigned xA = __shfl_xor(A, 32), xB = __shfl_xor(B, 32);      \
                unsigned xC = __shfl_xor(C, 32), xD = __shfl_xor(Dw, 32);     \
                unsigned w0 = hi ? xC : A, w1 = hi ? xD : B;                  \
                unsigned w2 = hi ? C : xA, w3 = hi ? Dw : xB;                 \
                bq[qb][ks] = (u32x4){w0, w1, w2, w3};                         \
            }                                                                 \
        }                                                                     \
    } while (0)

#define PV_TILE do {                                                          \
        PRIO1;                                                                \
        _Pragma("unroll")                                                     \
        for (int ks = 0; ks < 4; ++ks) {                                      \
            union { u32x4 u; bf16x8 v; } c0, c1;                              \
            c0.u = bq[0][ks]; c1.u = bq[1][ks];                               \
            o[0][0] = mfma32(vf[0][ks], c0.v, o[0][0]);                       \
            o[0][1] = mfma32(vf[0][ks], c1.v, o[0][1]);                       \
            o[1][0] = mfma32(vf[1][ks], c0.v, o[1][0]);                       \
            o[1][1] = mfma32(vf[1][ks], c1.v, o[1][1]);                       \
        }                                                                     \
        PRIO0;                                                                \
    } while (0)

    KLOAD(0);
    for (int kt = 0; kt < 32; ++kt) {
        VLOAD(kt);                 // needed after softmax; latency covered by QK+sm
        QK_TILE;                   // consumes kf (issued last iter / prologue)
        if (kt < 31) KLOAD(kt + 1);// reload kf; covered by sm + PV
        MASK_TILE(kt);
        SM_PACK;
        PV_TILE;
    }

    // ---- epilogue: O^T -> LDS transpose -> coalesced bf16 store ----
#pragma unroll
    for (int qb = 0; qb < 2; ++qb) {
        float inv = 1.f / l_run[qb];
        bf16* ob = &Ob[w][0];
#pragma unroll
        for (int db = 0; db < 2; ++db) {
            float* oo = (float*)&o[db][qb];
#pragma unroll
            for (int r = 0; r < 16; ++r) {
                int d = db * 32 + (r & 3) + 8 * (r >> 2) + 4 * hi;
                ob[l31 * 72 + d] = (bf16)(oo[r] * inv);
            }
        }
#pragma unroll
        for (int i = 0; i < 2; ++i)
#pragma unroll
            for (int half = 0; half < 2; ++half) {
                int ql = i * 16 + (lane >> 2);
                int d8 = (lane & 3) * 8 + half * 32;
                bf16x8 vv = *(const bf16x8*)(ob + ql * 72 + d8);
                *(bf16x8*)(ctx + (nbase + q0 + qb * 32 + ql) * 512 + headoff + d8) = vv;
            }
    }
#undef KLOAD
#undef VLOAD
#undef QK_TILE
#undef MASK_TILE
#undef SM_PACK
#undef PV_TILE
}

// ---------------------------------------------------------------------------
extern "C" void kernel_launch(void* const* d_in, const int* in_sizes, int n_in,
                              void* d_out, int out_size, void* d_ws, size_t ws_size,
                              hipStream_t stream) {
    (void)in_sizes; (void)n_in; (void)out_size; (void)ws_size;
    const float* values = (const float*)d_in[0];
    const float* keys   = (const float*)d_in[1];
    const float* query  = (const float*)d_in[2];
    const int*   mask   = (const int*)d_in[3];
    const float* Wv = (const float*)d_in[4];
    const float* Wk = (const float*)d_in[5];
    const float* Wq = (const float*)d_in[6];
    const float* Wo = (const float*)d_in[7];
    const float* bo = (const float*)d_in[8];
    float* out = (float*)d_out;

    char* ws = (char*)d_ws;
    bf16* wt  = (bf16*)(ws);                       //  2 MB: 4 x [512][512]
    bf16* Qb  = (bf16*)(ws + ((size_t)2  << 20));  // 16 MB
    bf16* Kb  = (bf16*)(ws + ((size_t)18 << 20));  // 16 MB
    bf16* VbT = (bf16*)(ws + ((size_t)34 << 20));  // 16 MB, [n][d][key]
    bf16* Cb  = (bf16*)(ws + ((size_t)50 << 20));  // 16 MB

    prep_weights<<<4096, 256, 0, stream>>>(Wv, Wk, Wq, Wo, wt);
    gemm_kernel<true, false, true ><<<dim3(128, 4), 256, 0, stream>>>(values, wt,              VbT, nullptr);
    gemm_kernel<true, false, false><<<dim3(128, 4), 256, 0, stream>>>(keys,   wt + 262144,     Kb,  nullptr);
    gemm_kernel<true, false, false><<<dim3(128, 4), 256, 0, stream>>>(query,  wt + 2 * 262144, Qb,  nullptr);
    attn_kernel<<<dim3(8, 8, 4), 512, 0, stream>>>(Qb, Kb, VbT, mask, Cb);
    gemm_kernel<false, true, false><<<dim3(128, 4), 256, 0, stream>>>(Cb, wt + 3 * 262144, out, bo);
}